// Round 1
// baseline (700.139 us; speedup 1.0000x reference)
//
#include <hip/hip_runtime.h>
#include <math.h>

#define IDIM 1024
#define EDIM 256
#define NB 4
#define NT 2048

#define NEG_BIG (-1e30f)

// ---------------- Kernel 1: QKV projection (fp32 tiled GEMM) ----------------
// X[8192,1024] @ W[1024,256] + b -> Out[8192,256]; blockIdx.z selects q/k/v.
// BM=64, BN=64, BK=16, 256 threads, 4x4 accum per thread.
__global__ __launch_bounds__(256) void qkv_proj(
    const float* __restrict__ X,
    const float* __restrict__ Wq, const float* __restrict__ bq,
    const float* __restrict__ Wk, const float* __restrict__ bk,
    const float* __restrict__ Wv, const float* __restrict__ bv,
    float* __restrict__ Qo, float* __restrict__ Ko, float* __restrict__ Vo)
{
    __shared__ float Xs[16][68];  // [k][m], +4 pad: conflict-free transpose scatter
    __shared__ float Ws[16][68];  // [k][n]

    const int z = blockIdx.z;
    const float* __restrict__ W    = (z == 0) ? Wq : (z == 1) ? Wk : Wv;
    const float* __restrict__ bias = (z == 0) ? bq : (z == 1) ? bk : bv;
    float* __restrict__ Out        = (z == 0) ? Qo : (z == 1) ? Ko : Vo;

    const int tid = threadIdx.x;
    const int tx = tid & 15;
    const int ty = tid >> 4;
    const int m0 = blockIdx.y * 64;
    const int n0 = blockIdx.x * 64;

    const int lxr = tid >> 2;          // 0..63
    const int lxk = (tid & 3) * 4;     // 0,4,8,12
    const int lwr = tid >> 4;          // 0..15
    const int lwc = (tid & 15) * 4;    // 0..60

    float acc[4][4] = {};

    for (int kt = 0; kt < IDIM; kt += 16) {
        float4 xv = *(const float4*)(X + (size_t)(m0 + lxr) * IDIM + kt + lxk);
        Xs[lxk + 0][lxr] = xv.x;
        Xs[lxk + 1][lxr] = xv.y;
        Xs[lxk + 2][lxr] = xv.z;
        Xs[lxk + 3][lxr] = xv.w;
        *(float4*)&Ws[lwr][lwc] =
            *(const float4*)(W + (size_t)(kt + lwr) * EDIM + n0 + lwc);
        __syncthreads();
        #pragma unroll
        for (int k = 0; k < 16; ++k) {
            float4 a  = *(const float4*)&Xs[k][4 * ty];
            float4 w4 = *(const float4*)&Ws[k][4 * tx];
            const float* ap = (const float*)&a;
            const float* wp = (const float*)&w4;
            #pragma unroll
            for (int i = 0; i < 4; ++i)
                #pragma unroll
                for (int j = 0; j < 4; ++j)
                    acc[i][j] = fmaf(ap[i], wp[j], acc[i][j]);
        }
        __syncthreads();
    }

    float4 bb = *(const float4*)(bias + n0 + 4 * tx);
    const float* bp = (const float*)&bb;
    #pragma unroll
    for (int i = 0; i < 4; ++i) {
        float4 o;
        float* op = (float*)&o;
        #pragma unroll
        for (int j = 0; j < 4; ++j) op[j] = acc[i][j] + bp[j];
        *(float4*)(Out + (size_t)(m0 + 4 * ty + i) * EDIM + n0 + 4 * tx) = o;
    }
}

// ---------------- Kernel 2: flash attention, fp32 ----------------
// BM=32 q-rows per block, BN=64 kv per tile. 256 threads.
// Thread (tx=tid&15, ty=tid>>4) owns S rows {ty, ty+16} x cols 4tx..4tx+3,
// and O rows {ty,ty+16} x e in {4tx+64j : j=0..3}.
#define BM 32
#define BN 64
#define QPAD 260   // Q row stride (floats); 260*4B mult of 16 ; 260%32=4 -> conflict-free
#define KST 68     // Ks_t[e][c] row stride (e rows = 64)
#define VST 260    // Vs[c][e] row stride (c rows = 16)
#define PST 68

__global__ __launch_bounds__(256) void attn_flash(
    const float* __restrict__ Qg, const float* __restrict__ Kg,
    const float* __restrict__ Vg, float* __restrict__ outg)
{
    __shared__ float Qs[BM * QPAD];   // 33280 B
    __shared__ float KV[64 * KST];    // 17408 B (union: Ks_t 64x68 / Vs 16x260)
    __shared__ float Ps[BM * PST];    // 8704 B   -> total 59392 B

    const int tid = threadIdx.x;
    const int id = blockIdx.x;
    // XCD swizzle: xcd = id%8; batch = (id>>1)&3 so each XCD streams one batch's K/V
    const int b  = (id >> 1) & 3;
    const int qt = (id & 1) * 32 + (id >> 3);

    const float* Qb = Qg + ((size_t)b * NT + (size_t)qt * BM) * EDIM;
    const float* Kb = Kg + (size_t)b * NT * EDIM;
    const float* Vb = Vg + (size_t)b * NT * EDIM;
    float* outb = outg + ((size_t)b * NT + (size_t)qt * BM) * EDIM;

    const int tx = tid & 15;
    const int ty = tid >> 4;
    const int r0 = ty, r1 = ty + 16;

    const float fold = 46.1662413084468283f;  // 32 * log2(e); exp2(q'.k - m) == softmax exp

    // load Q tile, pre-scaled
    #pragma unroll
    for (int i = 0; i < 8; ++i) {
        int fid = i * 256 + tid;
        int row = fid >> 6;
        int c4  = (fid & 63) * 4;
        float4 qv = *(const float4*)(Qb + (size_t)row * EDIM + c4);
        qv.x *= fold; qv.y *= fold; qv.z *= fold; qv.w *= fold;
        *(float4*)&Qs[row * QPAD + c4] = qv;
    }

    float m0v = NEG_BIG, m1v = NEG_BIG, l0v = 0.f, l1v = 0.f;
    float accO[2][4][4] = {};

    for (int kc = 0; kc < NT; kc += BN) {
        float s[2][4] = {};
        // --- S tile = Q' K^T ---
        for (int ec = 0; ec < EDIM; ec += 64) {
            __syncthreads();  // protect KV vs previous phase readers
            #pragma unroll
            for (int i = 0; i < 4; ++i) {
                int fid = i * 256 + tid;
                int c  = fid >> 4;          // 0..63
                int e4 = (fid & 15) * 4;    // 0..60
                float4 kvv = *(const float4*)(Kb + (size_t)(kc + c) * EDIM + ec + e4);
                KV[(e4 + 0) * KST + c] = kvv.x;
                KV[(e4 + 1) * KST + c] = kvv.y;
                KV[(e4 + 2) * KST + c] = kvv.z;
                KV[(e4 + 3) * KST + c] = kvv.w;
            }
            __syncthreads();
            #pragma unroll 4
            for (int e4 = 0; e4 < 64; e4 += 4) {
                float4 a0 = *(const float4*)&Qs[r0 * QPAD + ec + e4];
                float4 a1 = *(const float4*)&Qs[r1 * QPAD + ec + e4];
                float4 kr[4];
                kr[0] = *(const float4*)&KV[(e4 + 0) * KST + 4 * tx];
                kr[1] = *(const float4*)&KV[(e4 + 1) * KST + 4 * tx];
                kr[2] = *(const float4*)&KV[(e4 + 2) * KST + 4 * tx];
                kr[3] = *(const float4*)&KV[(e4 + 3) * KST + 4 * tx];
                const float* a0p = (const float*)&a0;
                const float* a1p = (const float*)&a1;
                #pragma unroll
                for (int e = 0; e < 4; ++e) {
                    const float* kkp = (const float*)&kr[e];
                    float a0e = a0p[e], a1e = a1p[e];
                    #pragma unroll
                    for (int j = 0; j < 4; ++j) {
                        s[0][j] = fmaf(a0e, kkp[j], s[0][j]);
                        s[1][j] = fmaf(a1e, kkp[j], s[1][j]);
                    }
                }
            }
        }

        // --- online softmax update (base-2) ---
        float mx0 = fmaxf(fmaxf(s[0][0], s[0][1]), fmaxf(s[0][2], s[0][3]));
        float mx1 = fmaxf(fmaxf(s[1][0], s[1][1]), fmaxf(s[1][2], s[1][3]));
        #pragma unroll
        for (int off = 1; off < 16; off <<= 1) {
            mx0 = fmaxf(mx0, __shfl_xor(mx0, off));
            mx1 = fmaxf(mx1, __shfl_xor(mx1, off));
        }
        float mn0 = fmaxf(m0v, mx0), mn1 = fmaxf(m1v, mx1);
        float al0 = exp2f(m0v - mn0), al1 = exp2f(m1v - mn1);
        float p0[4], p1[4];
        float sum0 = 0.f, sum1 = 0.f;
        #pragma unroll
        for (int j = 0; j < 4; ++j) {
            p0[j] = exp2f(s[0][j] - mn0); sum0 += p0[j];
            p1[j] = exp2f(s[1][j] - mn1); sum1 += p1[j];
        }
        #pragma unroll
        for (int off = 1; off < 16; off <<= 1) {
            sum0 += __shfl_xor(sum0, off);
            sum1 += __shfl_xor(sum1, off);
        }
        l0v = l0v * al0 + sum0; m0v = mn0;
        l1v = l1v * al1 + sum1; m1v = mn1;
        *(float4*)&Ps[r0 * PST + 4 * tx] = make_float4(p0[0], p0[1], p0[2], p0[3]);
        *(float4*)&Ps[r1 * PST + 4 * tx] = make_float4(p1[0], p1[1], p1[2], p1[3]);
        #pragma unroll
        for (int j = 0; j < 4; ++j)
            #pragma unroll
            for (int k = 0; k < 4; ++k) {
                accO[0][j][k] *= al0;
                accO[1][j][k] *= al1;
            }

        // --- O += P V ---
        for (int cg = 0; cg < BN; cg += 16) {
            __syncthreads();  // Ps visible (first iter) + prior KV readers done
            #pragma unroll
            for (int i = 0; i < 4; ++i) {
                int fid = i * 256 + tid;
                int c  = fid >> 6;          // 0..15
                int e4 = (fid & 63) * 4;    // 0..252
                *(float4*)&KV[c * VST + e4] =
                    *(const float4*)(Vb + (size_t)(kc + cg + c) * EDIM + e4);
            }
            __syncthreads();
            #pragma unroll 4
            for (int c = 0; c < 16; ++c) {
                float pp0 = Ps[r0 * PST + cg + c];
                float pp1 = Ps[r1 * PST + cg + c];
                #pragma unroll
                for (int j = 0; j < 4; ++j) {
                    float4 vv = *(const float4*)&KV[c * VST + 4 * tx + 64 * j];
                    const float* vp = (const float*)&vv;
                    #pragma unroll
                    for (int k = 0; k < 4; ++k) {
                        accO[0][j][k] = fmaf(pp0, vp[k], accO[0][j][k]);
                        accO[1][j][k] = fmaf(pp1, vp[k], accO[1][j][k]);
                    }
                }
            }
        }
    }

    // --- normalize + store ---
    float rl0 = 1.0f / l0v, rl1 = 1.0f / l1v;
    #pragma unroll
    for (int j = 0; j < 4; ++j) {
        float4 o0, o1;
        float* o0p = (float*)&o0;
        float* o1p = (float*)&o1;
        #pragma unroll
        for (int k = 0; k < 4; ++k) {
            o0p[k] = accO[0][j][k] * rl0;
            o1p[k] = accO[1][j][k] * rl1;
        }
        *(float4*)(outb + (size_t)r0 * EDIM + 4 * tx + 64 * j) = o0;
        *(float4*)(outb + (size_t)r1 * EDIM + 4 * tx + 64 * j) = o1;
    }
}

extern "C" void kernel_launch(void* const* d_in, const int* in_sizes, int n_in,
                              void* d_out, int out_size, void* d_ws, size_t ws_size,
                              hipStream_t stream) {
    const float* x  = (const float*)d_in[0];
    const float* Wq = (const float*)d_in[1];
    const float* bq = (const float*)d_in[2];
    const float* Wk = (const float*)d_in[3];
    const float* bk = (const float*)d_in[4];
    const float* Wv = (const float*)d_in[5];
    const float* bv = (const float*)d_in[6];
    float* out = (float*)d_out;

    float* Qw = (float*)d_ws;                       // 8 MB
    float* Kw = Qw + (size_t)NB * NT * EDIM;        // 8 MB
    float* Vw = Kw + (size_t)NB * NT * EDIM;        // 8 MB (24 MB total ws)

    qkv_proj<<<dim3(4, 128, 3), 256, 0, stream>>>(x, Wq, bq, Wk, bk, Wv, bv, Qw, Kw, Vw);
    attn_flash<<<256, 256, 0, stream>>>(Qw, Kw, Vw, out);
}

// Round 2
// 420.951 us; speedup vs baseline: 1.6632x; 1.6632x over previous
//
#include <hip/hip_runtime.h>
#include <math.h>

#define IDIM 1024
#define EDIM 256
#define NB 4
#define NT 2048

typedef __attribute__((ext_vector_type(8))) short short8;
typedef __attribute__((ext_vector_type(4))) float f32x4;

#define MFMA16(A,B,C) __builtin_amdgcn_mfma_f32_16x16x32_bf16(A,B,C,0,0,0)

// RNE float->bf16
__device__ __forceinline__ unsigned short f2bf(float x){
    unsigned u = __builtin_bit_cast(unsigned, x);
    u += 0x7fffu + ((u >> 16) & 1u);
    return (unsigned short)(u >> 16);
}
__device__ __forceinline__ float bf2f(unsigned short h){
    unsigned u = ((unsigned)h) << 16;
    return __builtin_bit_cast(float, u);
}

// ---------------- Kernel 0: split W into W^T hi/lo bf16 ----------------
// W[1024][256] f32 -> WT[256][1024] bf16 (hi and, for q/k, lo residual).
__global__ __launch_bounds__(256) void split_w(
    const float* __restrict__ Wq, const float* __restrict__ Wk, const float* __restrict__ Wv,
    ushort* __restrict__ Wqh, ushort* __restrict__ Wql,
    ushort* __restrict__ Wkh, ushort* __restrict__ Wkl,
    ushort* __restrict__ Wvh)
{
    int u = blockIdx.x * 256 + threadIdx.x;      // 3*32768 total
    int z   = u >> 15;
    int rem = u & 32767;
    int ko  = rem >> 8;    // k-octet 0..127
    int e   = rem & 255;
    const float* W = (z == 0) ? Wq : (z == 1) ? Wk : Wv;
    ushort* Oh = (z == 0) ? Wqh : (z == 1) ? Wkh : Wvh;
    ushort* Ol = (z == 0) ? Wql : Wkl;
    union { ushort us[8]; uint4 v; } hi, lo;
    #pragma unroll
    for (int j = 0; j < 8; ++j) {
        float wv = W[(size_t)(ko * 8 + j) * 256 + e];
        unsigned short h = f2bf(wv);
        hi.us[j] = h;
        lo.us[j] = f2bf(wv - bf2f(h));
    }
    *(uint4*)(Oh + (size_t)e * 1024 + ko * 8) = hi.v;
    if (z < 2) *(uint4*)(Ol + (size_t)e * 1024 + ko * 8) = lo.v;
}

// ---------------- Kernel 1: QKV projection, split-bf16 MFMA ----------------
// Tile: 64 rows x 256 cols, BK=32, 256 threads (4 waves as 2x2 of 32x128).
// z=0: Q (scaled by 32*log2e, hi/lo out), z=1: K (hi/lo), z=2: V (bf16, transposed out).
__global__ __launch_bounds__(256) void qkv_proj(
    const float* __restrict__ X,
    const ushort* __restrict__ Wh_q, const ushort* __restrict__ Wl_q,
    const ushort* __restrict__ Wh_k, const ushort* __restrict__ Wl_k,
    const ushort* __restrict__ Wh_v,
    const float* __restrict__ bq, const float* __restrict__ bk, const float* __restrict__ bv,
    ushort* __restrict__ Qh, ushort* __restrict__ Ql,
    ushort* __restrict__ Kh, ushort* __restrict__ Kl,
    ushort* __restrict__ Vt)
{
    // fragment-major LDS: A unit = kq*68 + m (m 0..63), B unit = kq*265 + n (n 0..255)
    __shared__ ushort Ah[268 * 8], Al[268 * 8];
    __shared__ ushort Bh[1051 * 8], Bl[1051 * 8];

    const int tid = threadIdx.x;
    const int z = blockIdx.y;
    const int m0 = blockIdx.x * 64;
    const ushort* Wh = (z == 0) ? Wh_q : (z == 1) ? Wh_k : Wh_v;
    const ushort* Wl = (z == 0) ? Wl_q : Wl_k;   // unused for z==2

    const int ln = tid & 15, quad = (tid >> 4) & 3, w = tid >> 6;
    const int wr = w >> 1, wc = w & 1;

    f32x4 acc[2][8];
    #pragma unroll
    for (int mi = 0; mi < 2; ++mi)
        #pragma unroll
        for (int ni = 0; ni < 8; ++ni) acc[mi][ni] = (f32x4){0.f, 0.f, 0.f, 0.f};

    const int am = tid >> 2, ako = tid & 3;
    const float* xsrc = X + (size_t)(m0 + am) * IDIM + ako * 8;

    for (int kk = 0; kk < IDIM; kk += 32) {
        __syncthreads();
        {   // stage A: X rows -> hi/lo bf16, fragment-major
            const float* p = xsrc + kk;
            float4 x0 = *(const float4*)p;
            float4 x1 = *(const float4*)(p + 4);
            float xv[8] = {x0.x, x0.y, x0.z, x0.w, x1.x, x1.y, x1.z, x1.w};
            union { ushort us[8]; uint4 v; } hi, lo;
            #pragma unroll
            for (int j = 0; j < 8; ++j) {
                unsigned short h = f2bf(xv[j]);
                hi.us[j] = h;
                lo.us[j] = f2bf(xv[j] - bf2f(h));
            }
            int unit = ako * 68 + am;
            *(uint4*)(Ah + unit * 8) = hi.v;
            *(uint4*)(Al + unit * 8) = lo.v;
        }
        {   // stage B: W^T rows
            int kq = tid & 3, nb = tid >> 2;
            #pragma unroll
            for (int i = 0; i < 4; ++i) {
                int n = nb + 64 * i;
                int unit = kq * 265 + n;
                *(uint4*)(Bh + unit * 8) = *(const uint4*)(Wh + (size_t)n * 1024 + kk + kq * 8);
                if (z < 2)
                    *(uint4*)(Bl + unit * 8) = *(const uint4*)(Wl + (size_t)n * 1024 + kk + kq * 8);
            }
        }
        __syncthreads();

        short8 a_h[2], a_l[2];
        #pragma unroll
        for (int mi = 0; mi < 2; ++mi) {
            int au = quad * 68 + wr * 32 + mi * 16 + ln;
            a_h[mi] = *(const short8*)(Ah + au * 8);
            if (z < 2) a_l[mi] = *(const short8*)(Al + au * 8);
        }
        #pragma unroll
        for (int ni = 0; ni < 8; ++ni) {
            int bu = quad * 265 + wc * 128 + ni * 16 + ln;
            short8 b_h = *(const short8*)(Bh + bu * 8);
            if (z < 2) {
                short8 b_l = *(const short8*)(Bl + bu * 8);
                #pragma unroll
                for (int mi = 0; mi < 2; ++mi) {
                    acc[mi][ni] = MFMA16(a_h[mi], b_h, acc[mi][ni]);
                    acc[mi][ni] = MFMA16(a_h[mi], b_l, acc[mi][ni]);
                    acc[mi][ni] = MFMA16(a_l[mi], b_h, acc[mi][ni]);
                }
            } else {
                #pragma unroll
                for (int mi = 0; mi < 2; ++mi)
                    acc[mi][ni] = MFMA16(a_h[mi], b_h, acc[mi][ni]);
            }
        }
    }

    // epilogue
    const float scale = (z == 0) ? 46.16624130844683f : 1.0f;  // 32*log2(e) folded into Q
    if (z < 2) {
        ushort* OH = (z == 0) ? Qh : Kh;
        ushort* OL = (z == 0) ? Ql : Kl;
        const float* bias = (z == 0) ? bq : bk;
        #pragma unroll
        for (int ni = 0; ni < 8; ++ni) {
            int e = wc * 128 + ni * 16 + ln;
            float bb = bias[e];
            #pragma unroll
            for (int mi = 0; mi < 2; ++mi)
                #pragma unroll
                for (int r = 0; r < 4; ++r) {
                    int m = m0 + wr * 32 + mi * 16 + quad * 4 + r;
                    float v = (acc[mi][ni][r] + bb) * scale;
                    unsigned short h = f2bf(v);
                    OH[(size_t)m * 256 + e] = h;
                    OL[(size_t)m * 256 + e] = f2bf(v - bf2f(h));
                }
        }
    } else {
        #pragma unroll
        for (int ni = 0; ni < 8; ++ni) {
            int e = wc * 128 + ni * 16 + ln;
            float bb = bv[e];
            #pragma unroll
            for (int mi = 0; mi < 2; ++mi) {
                int mb = m0 + wr * 32 + mi * 16 + quad * 4;
                union { ushort us[4]; uint2 v; } pk;
                #pragma unroll
                for (int r = 0; r < 4; ++r) pk.us[r] = f2bf(acc[mi][ni][r] + bb);
                *(uint2*)(Vt + (size_t)e * 8192 + mb) = pk.v;   // V^T[e][global row]
            }
        }
    }
}

// ---------------- Kernel 2: flash attention, MFMA ----------------
// BM=32 q-rows/block, BN=256 kv-tile, 256 threads; wave w owns kv/e range w*64..
#define ATTN_LDS 119552

__global__ __launch_bounds__(256) void attn(
    const ushort* __restrict__ Qh, const ushort* __restrict__ Ql,
    const ushort* __restrict__ Kh, const ushort* __restrict__ Kl,
    const ushort* __restrict__ Vt, float* __restrict__ out)
{
    extern __shared__ char smem[];
    ushort* Qh_s = (ushort*)smem;            // 32ko x (33 units): 8448 ushorts
    ushort* Ql_s = Qh_s + 8448;
    ushort* Kh_s = Ql_s + 8448;              // 8kq x (265 units): 16960 ushorts (also V)
    ushort* Kl_s = Kh_s + 16960;
    ushort* P_s  = Kl_s + 16960;             // 8448
    float*  rs   = (float*)(P_s + 8448);     // 4 waves x 32 rows
    float*  ss   = rs + 128;

    const int tid = threadIdx.x;
    const int ln = tid & 15, quad = (tid >> 4) & 3, w = tid >> 6;
    const int id = blockIdx.x;
    const int b  = (id >> 1) & 3;                    // XCD pair -> batch
    const int qt = (id & 1) * 32 + (id >> 3);
    const size_t qrow0 = (size_t)b * NT + (size_t)qt * 32;
    const size_t kvb   = (size_t)b * NT;

    {   // stage Q hi/lo fragment-major (unit = ko*33 + m)
        int m = tid >> 3;
        #pragma unroll
        for (int i = 0; i < 4; ++i) {
            int ko = (tid & 7) + 8 * i;
            int unit = ko * 33 + m;
            *(uint4*)(Qh_s + unit * 8) = *(const uint4*)(Qh + (qrow0 + m) * 256 + ko * 8);
            *(uint4*)(Ql_s + unit * 8) = *(const uint4*)(Ql + (qrow0 + m) * 256 + ko * 8);
        }
    }

    float m_r[2][4], l_r[2][4];
    f32x4 o[2][4];
    #pragma unroll
    for (int mi = 0; mi < 2; ++mi)
        #pragma unroll
        for (int r = 0; r < 4; ++r) { m_r[mi][r] = -1e30f; l_r[mi][r] = 0.f; }
    #pragma unroll
    for (int mi = 0; mi < 2; ++mi)
        #pragma unroll
        for (int ni = 0; ni < 4; ++ni) o[mi][ni] = (f32x4){0.f, 0.f, 0.f, 0.f};

    for (int kt = 0; kt < 8; ++kt) {
        const size_t kv0 = kvb + (size_t)kt * 256;
        f32x4 s[2][4];
        #pragma unroll
        for (int mi = 0; mi < 2; ++mi)
            #pragma unroll
            for (int ni = 0; ni < 4; ++ni) s[mi][ni] = (f32x4){0.f, 0.f, 0.f, 0.f};

        // ---- S = Q'.K^T over e in 4 stages of 64 ----
        for (int es = 0; es < 4; ++es) {
            __syncthreads();
            {
                int kq = tid & 7, nb = tid >> 3;
                #pragma unroll
                for (int i = 0; i < 8; ++i) {
                    int n = nb + 32 * i;
                    int unit = kq * 265 + n;
                    size_t src = (kv0 + n) * 256 + es * 64 + kq * 8;
                    *(uint4*)(Kh_s + unit * 8) = *(const uint4*)(Kh + src);
                    *(uint4*)(Kl_s + unit * 8) = *(const uint4*)(Kl + src);
                }
            }
            __syncthreads();
            #pragma unroll
            for (int ks = 0; ks < 2; ++ks) {
                int koq = es * 8 + ks * 4 + quad;
                int kqL = ks * 4 + quad;
                short8 ah[2], al[2];
                #pragma unroll
                for (int mi = 0; mi < 2; ++mi) {
                    int un = koq * 33 + mi * 16 + ln;
                    ah[mi] = *(const short8*)(Qh_s + un * 8);
                    al[mi] = *(const short8*)(Ql_s + un * 8);
                }
                #pragma unroll
                for (int ni = 0; ni < 4; ++ni) {
                    int n = w * 64 + ni * 16 + ln;
                    int bu = kqL * 265 + n;
                    short8 bh = *(const short8*)(Kh_s + bu * 8);
                    short8 bl = *(const short8*)(Kl_s + bu * 8);
                    #pragma unroll
                    for (int mi = 0; mi < 2; ++mi) {
                        s[mi][ni] = MFMA16(ah[mi], bh, s[mi][ni]);
                        s[mi][ni] = MFMA16(ah[mi], bl, s[mi][ni]);
                        s[mi][ni] = MFMA16(al[mi], bh, s[mi][ni]);
                    }
                }
            }
        }

        // ---- online softmax (base-2; scale folded into Q) ----
        float mt[2][4];
        #pragma unroll
        for (int mi = 0; mi < 2; ++mi)
            #pragma unroll
            for (int r = 0; r < 4; ++r)
                mt[mi][r] = fmaxf(fmaxf(s[mi][0][r], s[mi][1][r]), fmaxf(s[mi][2][r], s[mi][3][r]));
        #pragma unroll
        for (int mask = 1; mask < 16; mask <<= 1)
            #pragma unroll
            for (int mi = 0; mi < 2; ++mi)
                #pragma unroll
                for (int r = 0; r < 4; ++r)
                    mt[mi][r] = fmaxf(mt[mi][r], __shfl_xor(mt[mi][r], mask));
        if (ln == 0) {
            #pragma unroll
            for (int mi = 0; mi < 2; ++mi)
                #pragma unroll
                for (int r = 0; r < 4; ++r)
                    rs[w * 32 + mi * 16 + quad * 4 + r] = mt[mi][r];
        }
        __syncthreads();
        float alpha[2][4];
        #pragma unroll
        for (int mi = 0; mi < 2; ++mi)
            #pragma unroll
            for (int r = 0; r < 4; ++r) {
                int row = mi * 16 + quad * 4 + r;
                float mtile = fmaxf(fmaxf(rs[row], rs[32 + row]), fmaxf(rs[64 + row], rs[96 + row]));
                float mnew = fmaxf(m_r[mi][r], mtile);
                alpha[mi][r] = exp2f(m_r[mi][r] - mnew);
                m_r[mi][r] = mnew;
            }
        float ps[2][4] = {};
        #pragma unroll
        for (int ni = 0; ni < 4; ++ni) {
            int col = w * 64 + ni * 16 + ln;
            #pragma unroll
            for (int mi = 0; mi < 2; ++mi)
                #pragma unroll
                for (int r = 0; r < 4; ++r) {
                    float p = exp2f(s[mi][ni][r] - m_r[mi][r]);
                    ps[mi][r] += p;
                    P_s[((col >> 3) * 33 + (mi * 16 + quad * 4 + r)) * 8 + (col & 7)] = f2bf(p);
                }
        }
        #pragma unroll
        for (int mask = 1; mask < 16; mask <<= 1)
            #pragma unroll
            for (int mi = 0; mi < 2; ++mi)
                #pragma unroll
                for (int r = 0; r < 4; ++r)
                    ps[mi][r] += __shfl_xor(ps[mi][r], mask);
        if (ln == 0) {
            #pragma unroll
            for (int mi = 0; mi < 2; ++mi)
                #pragma unroll
                for (int r = 0; r < 4; ++r)
                    ss[w * 32 + mi * 16 + quad * 4 + r] = ps[mi][r];
        }
        #pragma unroll
        for (int mi = 0; mi < 2; ++mi)
            #pragma unroll
            for (int ni = 0; ni < 4; ++ni)
                #pragma unroll
                for (int r = 0; r < 4; ++r)
                    o[mi][ni][r] *= alpha[mi][r];
        __syncthreads();
        #pragma unroll
        for (int mi = 0; mi < 2; ++mi)
            #pragma unroll
            for (int r = 0; r < 4; ++r) {
                int row = mi * 16 + quad * 4 + r;
                float lt = ss[row] + ss[32 + row] + ss[64 + row] + ss[96 + row];
                l_r[mi][r] = l_r[mi][r] * alpha[mi][r] + lt;
            }

        // ---- O += P.V over kv in 4 stages of 64 (V reuses Kh_s) ----
        for (int vs = 0; vs < 4; ++vs) {
            __syncthreads();
            {
                int kq = tid & 7, eb = tid >> 3;
                #pragma unroll
                for (int i = 0; i < 8; ++i) {
                    int e = eb + 32 * i;
                    int unit = kq * 265 + e;
                    *(uint4*)(Kh_s + unit * 8) =
                        *(const uint4*)(Vt + (size_t)e * 8192 + kv0 + vs * 64 + kq * 8);
                }
            }
            __syncthreads();
            #pragma unroll
            for (int ks = 0; ks < 2; ++ks) {
                int ksv = vs * 2 + ks;
                int koP = ksv * 4 + quad;
                int kqL = ks * 4 + quad;
                short8 ap[2];
                #pragma unroll
                for (int mi = 0; mi < 2; ++mi)
                    ap[mi] = *(const short8*)(P_s + (koP * 33 + mi * 16 + ln) * 8);
                #pragma unroll
                for (int ni = 0; ni < 4; ++ni) {
                    int n = w * 64 + ni * 16 + ln;
                    short8 bv8 = *(const short8*)(Kh_s + (kqL * 265 + n) * 8);
                    #pragma unroll
                    for (int mi = 0; mi < 2; ++mi)
                        o[mi][ni] = MFMA16(ap[mi], bv8, o[mi][ni]);
                }
            }
        }
    }

    // ---- normalize + store ----
    #pragma unroll
    for (int mi = 0; mi < 2; ++mi)
        #pragma unroll
        for (int ni = 0; ni < 4; ++ni)
            #pragma unroll
            for (int r = 0; r < 4; ++r) {
                float v = o[mi][ni][r] / l_r[mi][r];
                out[(qrow0 + mi * 16 + quad * 4 + r) * 256 + w * 64 + ni * 16 + ln] = v;
            }
}

extern "C" void kernel_launch(void* const* d_in, const int* in_sizes, int n_in,
                              void* d_out, int out_size, void* d_ws, size_t ws_size,
                              hipStream_t stream) {
    const float* x  = (const float*)d_in[0];
    const float* Wq = (const float*)d_in[1];
    const float* bq = (const float*)d_in[2];
    const float* Wk = (const float*)d_in[3];
    const float* bk = (const float*)d_in[4];
    const float* Wv = (const float*)d_in[5];
    const float* bv = (const float*)d_in[6];
    float* out = (float*)d_out;

    const size_t NE = (size_t)NB * NT * EDIM;   // 2M elems
    ushort* Qh = (ushort*)d_ws;
    ushort* Ql = Qh + NE;
    ushort* Kh = Ql + NE;
    ushort* Kl = Kh + NE;
    ushort* Vt = Kl + NE;                        // [256][8192]
    ushort* Wqh = Vt + NE;
    ushort* Wql = Wqh + 256 * 1024;
    ushort* Wkh = Wql + 256 * 1024;
    ushort* Wkl = Wkh + 256 * 1024;
    ushort* Wvh = Wkl + 256 * 1024;              // total ws: 22.6 MB

    split_w<<<384, 256, 0, stream>>>(Wq, Wk, Wv, Wqh, Wql, Wkh, Wkl, Wvh);
    qkv_proj<<<dim3(128, 3), 256, 0, stream>>>(x, Wqh, Wql, Wkh, Wkl, Wvh,
                                               bq, bk, bv, Qh, Ql, Kh, Kl, Vt);
    attn<<<256, 256, ATTN_LDS, stream>>>(Qh, Ql, Kh, Kl, Vt, out);
}

// Round 3
// 340.039 us; speedup vs baseline: 2.0590x; 1.2379x over previous
//
#include <hip/hip_runtime.h>
#include <math.h>

#define IDIM 1024
#define EDIM 256
#define NB 4
#define NT 2048
#define NROW 8192

typedef __attribute__((ext_vector_type(8))) short short8;
typedef __attribute__((ext_vector_type(4))) float f32x4;

#define MFMA16(A,B,C) __builtin_amdgcn_mfma_f32_16x16x32_bf16(A,B,C,0,0,0)
#define GLD16(gsrc, ldst) __builtin_amdgcn_global_load_lds( \
    (const __attribute__((address_space(1))) unsigned int*)(gsrc), \
    (__attribute__((address_space(3))) unsigned int*)(ldst), 16, 0, 0)

__device__ __forceinline__ unsigned short f2bf(float x){
    unsigned u = __builtin_bit_cast(unsigned, x);
    u += 0x7fffu + ((u >> 16) & 1u);
    return (unsigned short)(u >> 16);
}
__device__ __forceinline__ float bf2f(unsigned short h){
    unsigned u = ((unsigned)h) << 16;
    return __builtin_bit_cast(float, u);
}

// ---------------- split X -> hi/lo bf16 ----------------
__global__ __launch_bounds__(256) void split_x(
    const float* __restrict__ X, ushort* __restrict__ Xh, ushort* __restrict__ Xl)
{
    size_t i = ((size_t)blockIdx.x * 256 + threadIdx.x) * 8;
    float4 a = *(const float4*)(X + i);
    float4 b = *(const float4*)(X + i + 4);
    float v[8] = {a.x, a.y, a.z, a.w, b.x, b.y, b.z, b.w};
    union { ushort us[8]; uint4 u; } hi, lo;
    #pragma unroll
    for (int j = 0; j < 8; ++j) {
        unsigned short h = f2bf(v[j]);
        hi.us[j] = h;
        lo.us[j] = f2bf(v[j] - bf2f(h));
    }
    *(uint4*)(Xh + i) = hi.u;
    *(uint4*)(Xl + i) = lo.u;
}

// ---------------- split W -> W^T hi/lo bf16 ----------------
__global__ __launch_bounds__(256) void split_w(
    const float* __restrict__ Wq, const float* __restrict__ Wk, const float* __restrict__ Wv,
    ushort* __restrict__ Wqh, ushort* __restrict__ Wql,
    ushort* __restrict__ Wkh, ushort* __restrict__ Wkl,
    ushort* __restrict__ Wvh)
{
    int u = blockIdx.x * 256 + threadIdx.x;
    int z   = u >> 15;
    int rem = u & 32767;
    int ko  = rem >> 8;
    int e   = rem & 255;
    const float* W = (z == 0) ? Wq : (z == 1) ? Wk : Wv;
    ushort* Oh = (z == 0) ? Wqh : (z == 1) ? Wkh : Wvh;
    ushort* Ol = (z == 0) ? Wql : Wkl;
    union { ushort us[8]; uint4 v; } hi, lo;
    #pragma unroll
    for (int j = 0; j < 8; ++j) {
        float wv = W[(size_t)(ko * 8 + j) * 256 + e];
        unsigned short h = f2bf(wv);
        hi.us[j] = h;
        lo.us[j] = f2bf(wv - bf2f(h));
    }
    *(uint4*)(Oh + (size_t)e * 1024 + ko * 8) = hi.v;
    if (z < 2) *(uint4*)(Ol + (size_t)e * 1024 + ko * 8) = lo.v;
}

// ---------------- QKV projection: 128x128 tile, global_load_lds ----------------
__global__ __launch_bounds__(256, 2) void qkv_proj(
    const ushort* __restrict__ Xh, const ushort* __restrict__ Xl,
    const ushort* __restrict__ Wh_q, const ushort* __restrict__ Wl_q,
    const ushort* __restrict__ Wh_k, const ushort* __restrict__ Wl_k,
    const ushort* __restrict__ Wh_v,
    const float* __restrict__ bq, const float* __restrict__ bk, const float* __restrict__ bv,
    ushort* __restrict__ Qh, ushort* __restrict__ Ql,
    ushort* __restrict__ Kh, ushort* __restrict__ Kl,
    ushort* __restrict__ Vt)
{
    __shared__ ushort AhL[4096], AlL[4096], BhL[4096], BlL[4096]; // unit = kq*128 + m

    const int tid = threadIdx.x;
    const int lane = tid & 63, w = tid >> 6;
    const int ln = tid & 15, quad = (tid >> 4) & 3;
    const int wr = w >> 1, wc = w & 1;
    const int z = blockIdx.z;
    const int n0 = blockIdx.x * 128;
    const int m0 = blockIdx.y * 128;
    const ushort* Wh = (z == 0) ? Wh_q : (z == 1) ? Wh_k : Wh_v;
    const ushort* Wl = (z == 0) ? Wl_q : Wl_k;

    f32x4 acc[4][4];
    #pragma unroll
    for (int mi = 0; mi < 4; ++mi)
        #pragma unroll
        for (int ni = 0; ni < 4; ++ni) acc[mi][ni] = (f32x4){0.f, 0.f, 0.f, 0.f};

    const ushort* A0 = Xh + (size_t)(m0 + lane) * IDIM + w * 8;
    const ushort* A1 = Xh + (size_t)(m0 + 64 + lane) * IDIM + w * 8;
    const ushort* A0l = Xl + (size_t)(m0 + lane) * IDIM + w * 8;
    const ushort* A1l = Xl + (size_t)(m0 + 64 + lane) * IDIM + w * 8;
    const ushort* B0 = Wh + (size_t)(n0 + lane) * IDIM + w * 8;
    const ushort* B1 = Wh + (size_t)(n0 + 64 + lane) * IDIM + w * 8;
    const ushort* B0l = Wl + (size_t)(n0 + lane) * IDIM + w * 8;
    const ushort* B1l = Wl + (size_t)(n0 + 64 + lane) * IDIM + w * 8;

    for (int kk = 0; kk < IDIM; kk += 32) {
        GLD16(A0 + kk, &AhL[(w * 128) * 8]);
        GLD16(A1 + kk, &AhL[(w * 128 + 64) * 8]);
        GLD16(B0 + kk, &BhL[(w * 128) * 8]);
        GLD16(B1 + kk, &BhL[(w * 128 + 64) * 8]);
        if (z < 2) {
            GLD16(A0l + kk, &AlL[(w * 128) * 8]);
            GLD16(A1l + kk, &AlL[(w * 128 + 64) * 8]);
            GLD16(B0l + kk, &BlL[(w * 128) * 8]);
            GLD16(B1l + kk, &BlL[(w * 128 + 64) * 8]);
        }
        __syncthreads();

        short8 ah[4], al[4];
        #pragma unroll
        for (int mi = 0; mi < 4; ++mi) {
            int un = quad * 128 + wr * 64 + mi * 16 + ln;
            ah[mi] = *(const short8*)&AhL[un * 8];
            if (z < 2) al[mi] = *(const short8*)&AlL[un * 8];
        }
        #pragma unroll
        for (int ni = 0; ni < 4; ++ni) {
            int bu = quad * 128 + wc * 64 + ni * 16 + ln;
            short8 bh = *(const short8*)&BhL[bu * 8];
            if (z < 2) {
                short8 bl = *(const short8*)&BlL[bu * 8];
                #pragma unroll
                for (int mi = 0; mi < 4; ++mi) {
                    acc[mi][ni] = MFMA16(ah[mi], bh, acc[mi][ni]);
                    acc[mi][ni] = MFMA16(ah[mi], bl, acc[mi][ni]);
                    acc[mi][ni] = MFMA16(al[mi], bh, acc[mi][ni]);
                }
            } else {
                #pragma unroll
                for (int mi = 0; mi < 4; ++mi)
                    acc[mi][ni] = MFMA16(ah[mi], bh, acc[mi][ni]);
            }
        }
        __syncthreads();
    }

    if (z < 2) {
        ushort* OH = (z == 0) ? Qh : Kh;
        ushort* OL = (z == 0) ? Ql : Kl;
        const float* bias = (z == 0) ? bq : bk;
        const float scale = (z == 0) ? 46.16624130844683f : 1.0f;  // 32*log2(e)
        #pragma unroll
        for (int ni = 0; ni < 4; ++ni) {
            int col = n0 + wc * 64 + ni * 16 + ln;
            float bb = bias[col];
            #pragma unroll
            for (int mi = 0; mi < 4; ++mi) {
                int mb = m0 + wr * 64 + mi * 16 + quad * 4;
                #pragma unroll
                for (int r = 0; r < 4; ++r) {
                    float v = (acc[mi][ni][r] + bb) * scale;
                    unsigned short h = f2bf(v);
                    OH[(size_t)(mb + r) * EDIM + col] = h;
                    OL[(size_t)(mb + r) * EDIM + col] = f2bf(v - bf2f(h));
                }
            }
        }
    } else {
        #pragma unroll
        for (int ni = 0; ni < 4; ++ni) {
            int col = n0 + wc * 64 + ni * 16 + ln;
            float bb = bv[col];
            #pragma unroll
            for (int mi = 0; mi < 4; ++mi) {
                int mb = m0 + wr * 64 + mi * 16 + quad * 4;
                union { ushort us[4]; uint2 v; } pk;
                #pragma unroll
                for (int r = 0; r < 4; ++r) pk.us[r] = f2bf(acc[mi][ni][r] + bb);
                *(uint2*)(Vt + (size_t)col * NROW + mb) = pk.v;
            }
        }
    }
}

// ---------------- attention: wave-autonomous, zero-barrier main loop ----------------
// 512 blocks x 4 waves. Wave = 16 q-rows x kv-quarter(512). kv tile BN=64.
// LDS: P slabs 4x2176B | O partials 4x16x260 f32 | m,l stats. One barrier total.
#define ATTN_LDS 75776

__global__ __launch_bounds__(256, 2) void attn(
    const ushort* __restrict__ Qh, const ushort* __restrict__ Ql,
    const ushort* __restrict__ Kh, const ushort* __restrict__ Kl,
    const ushort* __restrict__ Vt, float* __restrict__ out)
{
    extern __shared__ char smem[];
    const int tid = threadIdx.x;
    const int ln = tid & 15, quad = (tid >> 4) & 3, w = tid >> 6;
    ushort* Pslab = (ushort*)smem + w * 1088;        // unit = ko*17 + m (16B units)
    float* O_s = (float*)(smem + 8704);              // [w][16][260]
    float* m_s = (float*)(smem + 75264);             // [w][16]
    float* l_s = (float*)(smem + 75520);             // [w][16]

    const int id = blockIdx.x;
    const int b  = (id >> 1) & 3;                    // XCD-pair -> batch (K/V L2 locality)
    const int qt = (id >> 3) * 2 + (id & 1);
    const size_t qrow0 = (size_t)b * NT + (size_t)qt * 16;
    const int kv0 = b * NT + w * 512;                // this wave's kv quarter (global row)

    // Q hi fragments resident in registers; Q lo re-read per tile (L1/L2-hot)
    const ushort* qrowp  = Qh + (qrow0 + ln) * EDIM + quad * 8;
    const ushort* qlrowp = Ql + (qrow0 + ln) * EDIM + quad * 8;
    short8 qh[8];
    #pragma unroll
    for (int kc = 0; kc < 8; ++kc) qh[kc] = *(const short8*)(qrowp + kc * 32);

    float m_r[4], l_r[4];
    #pragma unroll
    for (int r = 0; r < 4; ++r) { m_r[r] = -3e38f; l_r[r] = 0.f; }
    f32x4 o[16];
    #pragma unroll
    for (int ni = 0; ni < 16; ++ni) o[ni] = (f32x4){0.f, 0.f, 0.f, 0.f};

    for (int t = 0; t < 8; ++t) {
        const int gkv = kv0 + t * 64;
        f32x4 s[4];
        #pragma unroll
        for (int ni = 0; ni < 4; ++ni) s[ni] = (f32x4){0.f, 0.f, 0.f, 0.f};

        // ---- S = Q'.K^T : B-fragments straight from global ----
        #pragma unroll
        for (int kc = 0; kc < 8; ++kc) {
            short8 al = *(const short8*)(qlrowp + kc * 32);
            #pragma unroll
            for (int ni = 0; ni < 4; ++ni) {
                size_t off = (size_t)(gkv + ni * 16 + ln) * EDIM + kc * 32 + quad * 8;
                short8 bh = *(const short8*)(Kh + off);
                short8 bl = *(const short8*)(Kl + off);
                s[ni] = MFMA16(qh[kc], bh, s[ni]);
                s[ni] = MFMA16(qh[kc], bl, s[ni]);
                s[ni] = MFMA16(al,     bh, s[ni]);
            }
        }

        // ---- online softmax (wave-local; rows live in 16-lane groups) ----
        float mt[4];
        #pragma unroll
        for (int r = 0; r < 4; ++r)
            mt[r] = fmaxf(fmaxf(s[0][r], s[1][r]), fmaxf(s[2][r], s[3][r]));
        #pragma unroll
        for (int mask = 1; mask < 16; mask <<= 1)
            #pragma unroll
            for (int r = 0; r < 4; ++r)
                mt[r] = fmaxf(mt[r], __shfl_xor(mt[r], mask));
        float alpha[4];
        #pragma unroll
        for (int r = 0; r < 4; ++r) {
            float mn = fmaxf(m_r[r], mt[r]);
            alpha[r] = exp2f(m_r[r] - mn);
            m_r[r] = mn;
        }
        float ls[4] = {0.f, 0.f, 0.f, 0.f};
        #pragma unroll
        for (int ni = 0; ni < 4; ++ni) {
            int colb = ni * 16 + ln;
            #pragma unroll
            for (int r = 0; r < 4; ++r) {
                float p = exp2f(s[ni][r] - m_r[r]);
                ls[r] += p;
                Pslab[((colb >> 3) * 17 + quad * 4 + r) * 8 + (colb & 7)] = f2bf(p);
            }
        }
        #pragma unroll
        for (int mask = 1; mask < 16; mask <<= 1)
            #pragma unroll
            for (int r = 0; r < 4; ++r)
                ls[r] += __shfl_xor(ls[r], mask);
        #pragma unroll
        for (int r = 0; r < 4; ++r) l_r[r] = l_r[r] * alpha[r] + ls[r];
        #pragma unroll
        for (int ni = 0; ni < 16; ++ni)
            #pragma unroll
            for (int r = 0; r < 4; ++r) o[ni][r] *= alpha[r];

        // ---- O += P.V (P via wave-private LDS slab; V fragments from global) ----
        short8 pf0 = *(const short8*)&Pslab[((0 + quad) * 17 + ln) * 8];
        short8 pf1 = *(const short8*)&Pslab[((4 + quad) * 17 + ln) * 8];
        #pragma unroll
        for (int ni = 0; ni < 16; ++ni) {
            const ushort* vb = Vt + (size_t)(ni * 16 + ln) * NROW + gkv + quad * 8;
            o[ni] = MFMA16(pf0, *(const short8*)vb, o[ni]);
            o[ni] = MFMA16(pf1, *(const short8*)(vb + 32), o[ni]);
        }
    }

    // ---- write partials, one barrier, merge 4 kv-quarters ----
    #pragma unroll
    for (int ni = 0; ni < 16; ++ni)
        #pragma unroll
        for (int r = 0; r < 4; ++r)
            O_s[(w * 16 + quad * 4 + r) * 260 + ni * 16 + ln] = o[ni][r];
    if (ln == 0) {
        #pragma unroll
        for (int r = 0; r < 4; ++r) {
            m_s[w * 16 + quad * 4 + r] = m_r[r];
            l_s[w * 16 + quad * 4 + r] = l_r[r];
        }
    }
    __syncthreads();

    const int row = tid >> 4, ec = (tid & 15) * 16;
    float mM = fmaxf(fmaxf(m_s[row], m_s[16 + row]), fmaxf(m_s[32 + row], m_s[48 + row]));
    float sc[4], denom = 0.f;
    #pragma unroll
    for (int w2 = 0; w2 < 4; ++w2) {
        sc[w2] = exp2f(m_s[w2 * 16 + row] - mM);
        denom += sc[w2] * l_s[w2 * 16 + row];
    }
    float inv = 1.0f / denom;
    #pragma unroll
    for (int g = 0; g < 4; ++g) {
        f32x4 accv = (f32x4){0.f, 0.f, 0.f, 0.f};
        #pragma unroll
        for (int w2 = 0; w2 < 4; ++w2) {
            f32x4 vv = *(const f32x4*)&O_s[(w2 * 16 + row) * 260 + ec + g * 4];
            accv += vv * sc[w2];
        }
        accv *= inv;
        *(f32x4*)(out + (qrow0 + row) * EDIM + ec + g * 4) = accv;
    }
}

extern "C" void kernel_launch(void* const* d_in, const int* in_sizes, int n_in,
                              void* d_out, int out_size, void* d_ws, size_t ws_size,
                              hipStream_t stream) {
    const float* x  = (const float*)d_in[0];
    const float* Wq = (const float*)d_in[1];
    const float* bq = (const float*)d_in[2];
    const float* Wk = (const float*)d_in[3];
    const float* bk = (const float*)d_in[4];
    const float* Wv = (const float*)d_in[5];
    const float* bv = (const float*)d_in[6];
    float* out = (float*)d_out;

    const size_t NE = (size_t)NB * NT * EDIM;        // 2M
    const size_t NX = (size_t)NROW * IDIM;           // 8.4M
    ushort* Xh = (ushort*)d_ws;
    ushort* Xl = Xh + NX;
    ushort* Qh = Xl + NX;
    ushort* Ql = Qh + NE;
    ushort* Kh = Ql + NE;
    ushort* Kl = Kh + NE;
    ushort* Vt = Kl + NE;                            // [256][8192]
    ushort* Wqh = Vt + NE;
    ushort* Wql = Wqh + 256 * 1024;
    ushort* Wkh = Wql + 256 * 1024;
    ushort* Wkl = Wkh + 256 * 1024;
    ushort* Wvh = Wkl + 256 * 1024;                  // ~57.1 MB total

    split_x<<<4096, 256, 0, stream>>>(x, Xh, Xl);
    split_w<<<384, 256, 0, stream>>>(Wq, Wk, Wv, Wqh, Wql, Wkh, Wkl, Wvh);
    qkv_proj<<<dim3(2, 64, 3), 256, 0, stream>>>(Xh, Xl, Wqh, Wql, Wkh, Wkl, Wvh,
                                                 bq, bk, bv, Qh, Ql, Kh, Kl, Vt);
    attn<<<512, 256, ATTN_LDS, stream>>>(Qh, Ql, Kh, Kl, Vt, out);
}